// Round 1
// baseline (1999.773 us; speedup 1.0000x reference)
//
#include <hip/hip_runtime.h>
#include <math.h>

#define NPTS 8192
#define KNB  16
#define C1   64
#define C2   128
#define NEG  0.2f
#define VEPS 1e-6f

// ======================= KNN =======================
// block: 256 threads = 32 queries x 8 candidate-chunks; grid: 256 blocks
__global__ __launch_bounds__(256) void knn_kernel(const float* __restrict__ x,
                                                  int* __restrict__ idx_out)
{
    __shared__ float  xs[NPTS];
    __shared__ float  ys[NPTS];
    __shared__ float  zs[NPTS];
    __shared__ double md[32][8][KNB];
    __shared__ int    mi[32][8][KNB];
    __shared__ int    heads[32][8];

    const int tid = threadIdx.x;
    for (int j = tid; j < NPTS; j += 256) {
        xs[j] = x[3*j+0]; ys[j] = x[3*j+1]; zs[j] = x[3*j+2];
    }
    __syncthreads();

    const int lq  = tid & 31;
    const int sub = tid >> 5;          // 0..7
    const int q   = blockIdx.x * 32 + lq;
    const float qx = xs[q], qy = ys[q], qz = zs[q];

    double bd[KNB]; int bi[KNB];
#pragma unroll
    for (int r = 0; r < KNB; ++r) { bd[r] = __builtin_inf(); bi[r] = 0x7fffffff; }

    const int j0 = sub * (NPTS/8);
    for (int j = j0; j < j0 + NPTS/8; ++j) {
        // f32 subtract (exact enough), f64 accumulate: ordering matches the
        // high-precision np reference's top_k to ~4e-10.
        const double dx = (double)(qx - xs[j]);
        const double dy = (double)(qy - ys[j]);
        const double dz = (double)(qz - zs[j]);
        const double d2 = dx*dx + dy*dy + dz*dz;
        if (d2 < bd[KNB-1]) {
            // fully-unrolled shift-insert: static indices -> registers
#pragma unroll
            for (int p = KNB-1; p > 0; --p) {
                const bool sh = d2 < bd[p-1];
                const bool pl = d2 < bd[p];
                const double nd = sh ? bd[p-1] : (pl ? d2 : bd[p]);
                const int    ni = sh ? bi[p-1] : (pl ? j  : bi[p]);
                bd[p] = nd; bi[p] = ni;
            }
            if (d2 < bd[0]) { bd[0] = d2; bi[0] = j; }
        }
    }
#pragma unroll
    for (int r = 0; r < KNB; ++r) { md[lq][sub][r] = bd[r]; mi[lq][sub][r] = bi[r]; }
    __syncthreads();

    if (sub == 0) {
        for (int s = 0; s < 8; ++s) heads[lq][s] = 0;
        for (int r = 0; r < KNB; ++r) {
            double best = __builtin_inf(); int bestj = 0x7fffffff; int bs = 0;
            for (int s = 0; s < 8; ++s) {
                const int h = heads[lq][s];
                const double dv = md[lq][s][h];
                const int    jv = mi[lq][s][h];
                if (dv < best || (dv == best && jv < bestj)) { best = dv; bestj = jv; bs = s; }
            }
            heads[lq][bs]++;
            idx_out[q*KNB + r] = bestj;   // ascending (d, j): matches top_k order
        }
    }
}

// ======================= shared GEMM tile =======================
// C (T x W) = A (T x W) @ B (W x W), all in LDS. W in {64,128}, W%4==0.
template<int W>
__device__ inline void tile_gemm(const float* __restrict__ A, const float* __restrict__ B,
                                 float* __restrict__ Cc, int T, int tid, int nt)
{
    const int total = T * W;
    for (int o = tid * 4; o < total; o += nt * 4) {
        const int t = o / W;
        const int d = o - t * W;           // multiple of 4
        const float* arow = A + t * W;
        float a0 = 0.f, a1 = 0.f, a2 = 0.f, a3 = 0.f;
        for (int c = 0; c < W; ++c) {
            const float av = arow[c];
            const float4 bv = *reinterpret_cast<const float4*>(B + c * W + d);
            a0 = fmaf(av, bv.x, a0);
            a1 = fmaf(av, bv.y, a1);
            a2 = fmaf(av, bv.z, a2);
            a3 = fmaf(av, bv.w, a3);
        }
        *reinterpret_cast<float4*>(Cc + o) = make_float4(a0, a1, a2, a3);
    }
}

// ======================= Kronecker step =======================
// v_{t+1}[i,a*PIN+b,c] = relu( (1/16 sum_k xg[i,k,a]*v_t[idx[ik],b,c]) @ W , U )
template<int PIN, bool FIRST, bool LAST>
__global__ void kron_step(const float* __restrict__ x, const int* __restrict__ idxs,
                          const float* __restrict__ vin,
                          const float* __restrict__ Wm, const float* __restrict__ Um,
                          float* __restrict__ vout,
                          const float* __restrict__ w4,
                          float* __restrict__ hv, float* __restrict__ gpart,
                          int pts_per_block)
{
    constexpr int T  = 3 * PIN;
    constexpr int TC = T * C1;
    __shared__ __align__(16) float sW[C1*C1];
    __shared__ __align__(16) float sU[C1*C1];
    __shared__ __align__(16) float bufA[TC];   // pre, then d
    __shared__ __align__(16) float bufB[TC];   // v (then relu(v) when LAST)
    __shared__ float xg[KNB*3];
    __shared__ int   ids[KNB];
    __shared__ float dotc[C1];
    __shared__ float psc[C1];
    __shared__ float mx[4];
    __shared__ float gl[LAST ? TC : 4];

    const int tid = threadIdx.x;
    const int nt  = blockDim.x;

    for (int e = tid; e < C1*C1; e += nt) { sW[e] = Wm[e]; sU[e] = Um[e]; }
    if (LAST) for (int e = tid; e < TC; e += nt) gl[e] = 0.f;
    __syncthreads();

    const int p0 = blockIdx.x * pts_per_block;
    for (int pi = 0; pi < pts_per_block; ++pi) {
        const int pt = p0 + pi;
        if (tid < KNB) ids[tid] = idxs[pt*KNB + tid];
        __syncthreads();
        if (tid < KNB*3) { const int k = tid / 3, a = tid - 3*k; xg[tid] = x[3*ids[k] + a]; }
        __syncthreads();

        if (FIRST) {
            if (tid < 3) {
                float s = 0.f;
                for (int k = 0; k < KNB; ++k) s += xg[k*3 + tid];
                mx[tid] = s * (1.0f/KNB);
            }
            __syncthreads();
            for (int e = tid; e < TC; e += nt) bufA[e] = mx[e >> 6];
        } else {
            const int PC = PIN * C1;   // 192 / 576 / 1728, all %4==0
            for (int e4 = tid * 4; e4 < PC; e4 += nt * 4) {
                float4 s0 = {0,0,0,0}, s1 = {0,0,0,0}, s2 = {0,0,0,0};
#pragma unroll
                for (int k = 0; k < KNB; ++k) {
                    const float4 val = *reinterpret_cast<const float4*>(vin + (size_t)ids[k]*PC + e4);
                    const float xa = xg[k*3+0], xb = xg[k*3+1], xc = xg[k*3+2];
                    s0.x = fmaf(xa, val.x, s0.x); s0.y = fmaf(xa, val.y, s0.y);
                    s0.z = fmaf(xa, val.z, s0.z); s0.w = fmaf(xa, val.w, s0.w);
                    s1.x = fmaf(xb, val.x, s1.x); s1.y = fmaf(xb, val.y, s1.y);
                    s1.z = fmaf(xb, val.z, s1.z); s1.w = fmaf(xb, val.w, s1.w);
                    s2.x = fmaf(xc, val.x, s2.x); s2.y = fmaf(xc, val.y, s2.y);
                    s2.z = fmaf(xc, val.z, s2.z); s2.w = fmaf(xc, val.w, s2.w);
                }
                const float inv = 1.0f / KNB;
                s0.x*=inv; s0.y*=inv; s0.z*=inv; s0.w*=inv;
                s1.x*=inv; s1.y*=inv; s1.z*=inv; s1.w*=inv;
                s2.x*=inv; s2.y*=inv; s2.z*=inv; s2.w*=inv;
                *reinterpret_cast<float4*>(bufA + e4)          = s0;
                *reinterpret_cast<float4*>(bufA + PC + e4)     = s1;
                *reinterpret_cast<float4*>(bufA + 2*PC + e4)   = s2;
            }
        }
        __syncthreads();
        tile_gemm<C1>(bufA, sW, bufB, T, tid, nt);   // v = pre @ W
        __syncthreads();
        tile_gemm<C1>(bufB, sU, bufA, T, tid, nt);   // d = v @ U
        __syncthreads();
        if (tid < C1) {
            float dt = 0.f, dn = 0.f;
            for (int t = 0; t < T; ++t) {
                const float vv = bufB[t*C1 + tid];
                const float dd = bufA[t*C1 + tid];
                dt = fmaf(vv, dd, dt);
                dn = fmaf(dd, dd, dn);
            }
            dotc[tid] = dt;
            psc[tid]  = dt / (dn + VEPS);
        }
        __syncthreads();
        if (!LAST) {
            for (int e = tid; e < TC; e += nt) {
                const int c = e & 63;
                const float vv = bufB[e], dd = bufA[e];
                const float rr = (dotc[c] >= 0.f) ? vv : fmaf(-psc[c], dd, vv);
                vout[(size_t)pt * TC + e] = NEG*vv + (1.f-NEG)*rr;
            }
        } else {
            for (int e = tid; e < TC; e += nt) {
                const int c = e & 63;
                const float vv = bufB[e], dd = bufA[e];
                const float rr = (dotc[c] >= 0.f) ? vv : fmaf(-psc[c], dd, vv);
                bufB[e] = NEG*vv + (1.f-NEG)*rr;
            }
            __syncthreads();
            for (int e = tid; e < TC; e += nt) gl[e] += bufB[e];
            // six k=4 trace pairs, weighted by w4[:, :64]  ->  hv (pt, 9, 64)
            for (int e = tid; e < 9*C1; e += nt) {
                const int pq = e >> 6, c = e & 63;
                const int p = pq / 3, qq = pq - 3*p;
                float tr0=0,tr1=0,tr2=0,tr3=0,tr4=0,tr5=0;
#pragma unroll
                for (int r = 0; r < 3; ++r) {
                    tr0 += bufB[(r*36 + p*3 + qq ) * C1 + c];   // (1,2)
                    tr1 += bufB[(r*30 + p*9 + qq ) * C1 + c];   // (1,3)
                    tr2 += bufB[(r*28 + p*9 + qq*3) * C1 + c];  // (1,4)
                    tr3 += bufB[(p*27 + r*12 + qq ) * C1 + c];  // (2,3)
                    tr4 += bufB[(p*27 + r*10 + qq*3) * C1 + c]; // (2,4)
                    tr5 += bufB[(p*27 + qq*9 + r*4 ) * C1 + c]; // (3,4)
                }
                const float acc = w4[0*C2 + c]*tr0 + w4[1*C2 + c]*tr1 + w4[2*C2 + c]*tr2
                                + w4[3*C2 + c]*tr3 + w4[4*C2 + c]*tr4 + w4[5*C2 + c]*tr5;
                hv[(size_t)pt * (9*C1) + e] = acc;
            }
        }
        __syncthreads();
    }
    if (LAST) {
        for (int e = tid; e < TC; e += nt) gpart[(size_t)blockIdx.x * TC + e] = gl[e];
    }
}

// ======================= g reduction + hg =======================
__global__ void reduce_g_kernel(const float* __restrict__ gpart, int nparts,
                                float* __restrict__ g)
{
    const int e = blockIdx.x * blockDim.x + threadIdx.x;
    if (e >= 81*C1) return;
    float s = 0.f;
    for (int b = 0; b < nparts; ++b) s += gpart[(size_t)b * (81*C1) + e];
    g[e] = s * (1.0f/NPTS);
}

__global__ void hg_kernel(const float* __restrict__ g, const float* __restrict__ w4,
                          float* __restrict__ hg)
{
    __shared__ float gs[81*C1];
    const int tid = threadIdx.x;
    for (int e = tid; e < 81*C1; e += blockDim.x) gs[e] = g[e];
    __syncthreads();
    for (int e = tid; e < 9*C1; e += blockDim.x) {
        const int pq = e >> 6, c = e & 63;
        const int p = pq / 3, qq = pq - 3*p;
        float tr0=0,tr1=0,tr2=0,tr3=0,tr4=0,tr5=0;
#pragma unroll
        for (int r = 0; r < 3; ++r) {
            tr0 += gs[(r*36 + p*3 + qq ) * C1 + c];
            tr1 += gs[(r*30 + p*9 + qq ) * C1 + c];
            tr2 += gs[(r*28 + p*9 + qq*3) * C1 + c];
            tr3 += gs[(p*27 + r*12 + qq ) * C1 + c];
            tr4 += gs[(p*27 + r*10 + qq*3) * C1 + c];
            tr5 += gs[(p*27 + qq*9 + r*4 ) * C1 + c];
        }
        hg[e] = w4[0*C2 + 64 + c]*tr0 + w4[1*C2 + 64 + c]*tr1 + w4[2*C2 + 64 + c]*tr2
              + w4[3*C2 + 64 + c]*tr3 + w4[4*C2 + 64 + c]*tr4 + w4[5*C2 + 64 + c]*tr5;
    }
}

// ======================= contraction head =======================
__global__ __launch_bounds__(256) void contract_kernel(const float* __restrict__ hv,
                                                       const float* __restrict__ hg,
                                                       const float* __restrict__ cW,
                                                       const float* __restrict__ cU,
                                                       const float* __restrict__ w2,
                                                       float* __restrict__ out,
                                                       int pts_per_block)
{
    __shared__ __align__(16) float sW[C2*C2];   // 64KB
    __shared__ __align__(16) float sU[C2*C2];   // 64KB
    __shared__ __align__(16) float h0[9*C2];
    __shared__ __align__(16) float h1[9*C2];
    __shared__ __align__(16) float h2[9*C2];
    __shared__ float hgs[9*C1];
    __shared__ float dotc[C2], psc[C2];

    const int tid = threadIdx.x, nt = blockDim.x;
    for (int e = tid; e < C2*C2; e += nt) { sW[e] = cW[e]; sU[e] = cU[e]; }
    for (int e = tid; e < 9*C1; e += nt) hgs[e] = hg[e];
    __syncthreads();

    const int p0 = blockIdx.x * pts_per_block;
    for (int pi = 0; pi < pts_per_block; ++pi) {
        const int pt = p0 + pi;
        for (int e = tid; e < 9*C2; e += nt) {
            const int t = e >> 7, c = e & 127;
            h0[e] = (c < C1) ? hv[(size_t)pt*(9*C1) + t*C1 + c] : hgs[t*C1 + (c - C1)];
        }
        __syncthreads();
        tile_gemm<C2>(h0, sW, h1, 9, tid, nt);   // h1 = h @ contr_W
        __syncthreads();
        tile_gemm<C2>(h1, sU, h2, 9, tid, nt);   // h2 = h1 @ contr_U  (the "d")
        __syncthreads();
        if (tid < C2) {
            float dt = 0.f, dn = 0.f;
            for (int t = 0; t < 9; ++t) {
                const float vv = h1[t*C2 + tid], dd = h2[t*C2 + tid];
                dt = fmaf(vv, dd, dt); dn = fmaf(dd, dd, dn);
            }
            dotc[tid] = dt; psc[tid] = dt / (dn + VEPS);
        }
        __syncthreads();
        if (tid < C2) {
            const int c = tid;
            float s = 0.f;
#pragma unroll
            for (int r = 0; r < 3; ++r) {
                const int t = r * 4;             // rows (0,0),(1,1),(2,2) of 3x3
                const float vv = h1[t*C2 + c], dd = h2[t*C2 + c];
                const float rr = (dotc[c] >= 0.f) ? vv : fmaf(-psc[c], dd, vv);
                s += NEG*vv + (1.f-NEG)*rr;
            }
            out[(size_t)pt*C2 + c] = w2[c] * s;
        }
        __syncthreads();
    }
}

// ======================= launcher =======================
extern "C" void kernel_launch(void* const* d_in, const int* in_sizes, int n_in,
                              void* d_out, int out_size, void* d_ws, size_t ws_size,
                              hipStream_t stream)
{
    (void)in_sizes; (void)n_in; (void)out_size; (void)ws_size;
    const float* x  = (const float*)d_in[0];
    const float* kW = (const float*)d_in[1];   // (4,64,64)
    const float* kU = (const float*)d_in[2];   // (4,64,64)
    const float* w4 = (const float*)d_in[3];   // (6,128)
    const float* cW = (const float*)d_in[4];   // (128,128)
    const float* cU = (const float*)d_in[5];   // (128,128)
    const float* w2 = (const float*)d_in[6];   // (1,128)
    float* out = (float*)d_out;

    char* ws = (char*)d_ws;
    size_t off = 0;
    auto alloc = [&](size_t bytes) -> void* {
        void* p = ws + off; off += (bytes + 255) & ~(size_t)255; return p;
    };
    int*   idx   = (int*)  alloc((size_t)NPTS*KNB*4);        // 512 KB
    float* v1    = (float*)alloc((size_t)NPTS*3*C1*4);       // 6.3 MB
    float* v2    = (float*)alloc((size_t)NPTS*9*C1*4);       // 18.9 MB (reused as hv)
    float* v3    = (float*)alloc((size_t)NPTS*27*C1*4);      // 56.6 MB
    float* gpart = (float*)alloc((size_t)256*81*C1*4);       // 5.3 MB
    float* g     = (float*)alloc((size_t)81*C1*4);
    float* hg    = (float*)alloc((size_t)9*C1*4);
    float* hv    = v2;   // v2 is dead once v3 exists

    knn_kernel<<<NPTS/32, 256, 0, stream>>>(x, idx);
    kron_step<1,  true,  false><<<512, 256, 0, stream>>>(x, idx, nullptr, kW,        kU,        v1, nullptr, nullptr, nullptr, 16);
    kron_step<3,  false, false><<<512, 256, 0, stream>>>(x, idx, v1,      kW+4096,   kU+4096,   v2, nullptr, nullptr, nullptr, 16);
    kron_step<9,  false, false><<<512, 256, 0, stream>>>(x, idx, v2,      kW+8192,   kU+8192,   v3, nullptr, nullptr, nullptr, 16);
    kron_step<27, false, true ><<<256, 512, 0, stream>>>(x, idx, v3,      kW+12288,  kU+12288,  nullptr, w4, hv, gpart, 32);
    reduce_g_kernel<<<(81*C1 + 255)/256, 256, 0, stream>>>(gpart, 256, g);
    hg_kernel<<<1, 256, 0, stream>>>(g, w4, hg);
    contract_kernel<<<256, 256, 0, stream>>>(hv, hg, cW, cU, w2, out, 32);
}

// Round 2
// 1555.940 us; speedup vs baseline: 1.2853x; 1.2853x over previous
//
#include <hip/hip_runtime.h>
#include <math.h>

#define NPTS 8192
#define KNB  16
#define C1   64
#define C2   128
#define NEG  0.2f
#define VEPS 1e-6f
#define NCH  32
#define CHSZ (NPTS/NCH)   // 256

// ======================= KNN phase 1: per-chunk top-16 =======================
// grid: 32 query-groups x 32 chunks = 1024 blocks, 256 threads (lane = query)
__global__ __launch_bounds__(256) void knn_part(const float* __restrict__ x,
                                                unsigned long long* __restrict__ parts)
{
    __shared__ __align__(16) float4 cpt[CHSZ];
    __shared__ unsigned long long sbuf[256 * 8];

    const int tid   = threadIdx.x;
    const int chunk = blockIdx.x & (NCH - 1);
    const int qg    = blockIdx.x >> 5;
    const int j0    = chunk * CHSZ;

    cpt[tid] = make_float4(x[3*(j0+tid)+0], x[3*(j0+tid)+1], x[3*(j0+tid)+2], 0.f);
    const int q = qg * 256 + tid;
    const float qx = x[3*q+0], qy = x[3*q+1], qz = x[3*q+2];
    __syncthreads();

    // sorted top-16 keys, ascending. key = (bits(f64 d2) & ~8191) | j  (exact (d2,j) order)
    unsigned long long bd[16];
#pragma unroll
    for (int r = 0; r < 16; ++r) bd[r] = ~0ull;
    int cnt = 0;
    unsigned long long* mybuf = sbuf + tid * 8;

    auto flush = [&]() {
#pragma unroll
        for (int s = 0; s < 8; ++s) {
            if (s < cnt) {
                const unsigned long long k = mybuf[s];
                if (k < bd[15]) {
#pragma unroll
                    for (int p2 = 15; p2 > 0; --p2) {
                        const bool sh = k < bd[p2-1];
                        const bool pl = k < bd[p2];
                        bd[p2] = sh ? bd[p2-1] : (pl ? k : bd[p2]);
                    }
                    if (k < bd[0]) bd[0] = k;
                }
            }
        }
        cnt = 0;
    };

    for (int jj = 0; jj < CHSZ; ++jj) {
        const float4 p = cpt[jj];
        const float dx = qx - p.x, dy = qy - p.y, dz = qz - p.z;
        const double ddx = (double)dx, ddy = (double)dy, ddz = (double)dz;
        const double d2 = ddx*ddx + ddy*ddy + ddz*ddz;
        const unsigned long long key =
            (((unsigned long long)__double_as_longlong(d2)) & ~8191ull)
            | (unsigned long long)(j0 + jj);
        if (key < bd[15]) { mybuf[cnt] = key; ++cnt; }   // stale gate: conservative, exact at flush
        if (__any(cnt >= 8)) flush();
    }
    flush();

#pragma unroll
    for (int r = 0; r < 16; ++r)
        parts[((size_t)chunk * KNB + r) * NPTS + q] = bd[r];   // coalesced in q
}

// ======================= KNN phase 2: 32-way sorted merge =======================
__global__ __launch_bounds__(256) void knn_merge(const unsigned long long* __restrict__ parts,
                                                 int* __restrict__ idx_out)
{
    __shared__ unsigned char heads[256][NCH];
    const int tid = threadIdx.x;
    const int q = blockIdx.x * 256 + tid;
    unsigned char* h = heads[tid];
#pragma unroll
    for (int c = 0; c < NCH; ++c) h[c] = 0;
    for (int r = 0; r < KNB; ++r) {
        unsigned long long best = ~0ull; int bc = 0;
#pragma unroll
        for (int c = 0; c < NCH; ++c) {
            const unsigned long long k = parts[((size_t)c * KNB + h[c]) * NPTS + q];
            if (k < best) { best = k; bc = c; }
        }
        h[bc]++;
        idx_out[q*KNB + r] = (int)(best & 8191ull);
    }
}

// ======================= GEMM tiles =======================
#define FMA4(ar, b0, b1, b2, b3, acc) \
    acc.x = fmaf(ar.x,b0.x, fmaf(ar.y,b1.x, fmaf(ar.z,b2.x, fmaf(ar.w,b3.x, acc.x)))); \
    acc.y = fmaf(ar.x,b0.y, fmaf(ar.y,b1.y, fmaf(ar.z,b2.y, fmaf(ar.w,b3.y, acc.y)))); \
    acc.z = fmaf(ar.x,b0.z, fmaf(ar.y,b1.z, fmaf(ar.z,b2.z, fmaf(ar.w,b3.z, acc.z)))); \
    acc.w = fmaf(ar.x,b0.w, fmaf(ar.y,b1.w, fmaf(ar.z,b2.w, fmaf(ar.w,b3.w, acc.w))));

// C (TPxW, stride SA) = A (TPxW, stride SA) @ B (WxW, stride W). TP%4==0.
// 4-row x 4-col register tile: 8 LDS b128 per 64 MACs/lane -> VALU-bound.
template<int W, int SA>
__device__ __forceinline__ void tile_gemm44(const float* __restrict__ A,
                                            const float* __restrict__ B,
                                            float* __restrict__ Cc,
                                            int TP, int tid, int nt)
{
    constexpr int DQ = W / 4;
    const int nunits = (TP >> 2) * DQ;
    for (int u = tid; u < nunits; u += nt) {
        const int tg = u / DQ;
        const int d  = (u - tg * DQ) * 4;
        const float* a0p = A + (tg*4+0)*SA;
        const float* a1p = A + (tg*4+1)*SA;
        const float* a2p = A + (tg*4+2)*SA;
        const float* a3p = A + (tg*4+3)*SA;
        float4 acc0 = {0,0,0,0}, acc1 = acc0, acc2 = acc0, acc3 = acc0;
        for (int c = 0; c < W; c += 4) {
            const float4 a0 = *reinterpret_cast<const float4*>(a0p + c);
            const float4 a1 = *reinterpret_cast<const float4*>(a1p + c);
            const float4 a2 = *reinterpret_cast<const float4*>(a2p + c);
            const float4 a3 = *reinterpret_cast<const float4*>(a3p + c);
            const float4 b0 = *reinterpret_cast<const float4*>(B + (c+0)*W + d);
            const float4 b1 = *reinterpret_cast<const float4*>(B + (c+1)*W + d);
            const float4 b2 = *reinterpret_cast<const float4*>(B + (c+2)*W + d);
            const float4 b3 = *reinterpret_cast<const float4*>(B + (c+3)*W + d);
            FMA4(a0, b0, b1, b2, b3, acc0);
            FMA4(a1, b0, b1, b2, b3, acc1);
            FMA4(a2, b0, b1, b2, b3, acc2);
            FMA4(a3, b0, b1, b2, b3, acc3);
        }
        *reinterpret_cast<float4*>(Cc + (tg*4+0)*SA + d) = acc0;
        *reinterpret_cast<float4*>(Cc + (tg*4+1)*SA + d) = acc1;
        *reinterpret_cast<float4*>(Cc + (tg*4+2)*SA + d) = acc2;
        *reinterpret_cast<float4*>(Cc + (tg*4+3)*SA + d) = acc3;
    }
}

// old scalar-A tile (used by contract kernel only, unchanged)
template<int W>
__device__ inline void tile_gemm(const float* __restrict__ A, const float* __restrict__ B,
                                 float* __restrict__ Cc, int T, int tid, int nt)
{
    const int total = T * W;
    for (int o = tid * 4; o < total; o += nt * 4) {
        const int t = o / W;
        const int d = o - t * W;
        const float* arow = A + t * W;
        float a0 = 0.f, a1 = 0.f, a2 = 0.f, a3 = 0.f;
        for (int c = 0; c < W; ++c) {
            const float av = arow[c];
            const float4 bv = *reinterpret_cast<const float4*>(B + c * W + d);
            a0 = fmaf(av, bv.x, a0);
            a1 = fmaf(av, bv.y, a1);
            a2 = fmaf(av, bv.z, a2);
            a3 = fmaf(av, bv.w, a3);
        }
        *reinterpret_cast<float4*>(Cc + o) = make_float4(a0, a1, a2, a3);
    }
}

// ======================= Kronecker step =======================
template<int PIN, bool FIRST, bool LAST>
__global__ __launch_bounds__(256) void kron_step(const float* __restrict__ x, const int* __restrict__ idxs,
                          const float* __restrict__ vin,
                          const float* __restrict__ Wm, const float* __restrict__ Um,
                          float* __restrict__ vout,
                          const float* __restrict__ w4,
                          float* __restrict__ hv, float* __restrict__ gpart,
                          int pts_per_block)
{
    constexpr int T  = 3 * PIN;
    constexpr int TP = (T + 3) & ~3;
    constexpr int SA = C1 + 4;           // padded stride: kills A-row bank conflicts
    constexpr int TC = T * C1;
    constexpr int NG = LAST ? (TC + 255) / 256 : 1;

    __shared__ __align__(16) float sW[C1*C1];
    __shared__ __align__(16) float sU[C1*C1];
    __shared__ __align__(16) float bufA[TP*SA];
    __shared__ __align__(16) float bufB[TP*SA];
    __shared__ float xg[KNB*3];
    __shared__ int   ids[KNB];
    __shared__ float dotc[C1], psc[C1];
    __shared__ float pdt[4][C1], pdn[4][C1];
    __shared__ float mx[4];

    const int tid = threadIdx.x;
    const int nt  = 256;

    for (int e = tid; e < C1*C1; e += nt) { sW[e] = Wm[e]; sU[e] = Um[e]; }
    // zero pad rows once (stay zero through both GEMMs: zero A rows -> zero C rows)
    for (int e = tid; e < (TP - T) * C1; e += nt) {
        const int r = T + (e >> 6), c = e & 63;
        bufA[r*SA + c] = 0.f; bufB[r*SA + c] = 0.f;
    }
    float gacc[NG];
#pragma unroll
    for (int i = 0; i < NG; ++i) gacc[i] = 0.f;
    __syncthreads();

    const int p0 = blockIdx.x * pts_per_block;
    for (int pi = 0; pi < pts_per_block; ++pi) {
        const int pt = p0 + pi;
        if (tid < KNB) ids[tid] = idxs[pt*KNB + tid];
        __syncthreads();
        if (tid < KNB*3) { const int k = tid / 3, a = tid - 3*k; xg[tid] = x[3*ids[k] + a]; }
        __syncthreads();

        if (FIRST) {
            if (tid < 3) {
                float s = 0.f;
                for (int k = 0; k < KNB; ++k) s += xg[k*3 + tid];
                mx[tid] = s * (1.0f/KNB);
            }
            __syncthreads();
            for (int e = tid; e < TC; e += nt) bufA[(e >> 6)*SA + (e & 63)] = mx[e >> 6];
        } else {
            const int PC = PIN * C1;
            for (int e4 = tid * 4; e4 < PC; e4 += nt * 4) {
                float4 s0 = {0,0,0,0}, s1 = {0,0,0,0}, s2 = {0,0,0,0};
#pragma unroll
                for (int k = 0; k < KNB; ++k) {
                    const float4 val = *reinterpret_cast<const float4*>(vin + (size_t)ids[k]*PC + e4);
                    const float xa = xg[k*3+0], xb = xg[k*3+1], xc = xg[k*3+2];
                    s0.x = fmaf(xa, val.x, s0.x); s0.y = fmaf(xa, val.y, s0.y);
                    s0.z = fmaf(xa, val.z, s0.z); s0.w = fmaf(xa, val.w, s0.w);
                    s1.x = fmaf(xb, val.x, s1.x); s1.y = fmaf(xb, val.y, s1.y);
                    s1.z = fmaf(xb, val.z, s1.z); s1.w = fmaf(xb, val.w, s1.w);
                    s2.x = fmaf(xc, val.x, s2.x); s2.y = fmaf(xc, val.y, s2.y);
                    s2.z = fmaf(xc, val.z, s2.z); s2.w = fmaf(xc, val.w, s2.w);
                }
                const float inv = 1.0f / KNB;
                s0.x*=inv; s0.y*=inv; s0.z*=inv; s0.w*=inv;
                s1.x*=inv; s1.y*=inv; s1.z*=inv; s1.w*=inv;
                s2.x*=inv; s2.y*=inv; s2.z*=inv; s2.w*=inv;
                const int b = e4 >> 6, c = e4 & 63;
                *reinterpret_cast<float4*>(bufA + (0*PIN + b)*SA + c) = s0;
                *reinterpret_cast<float4*>(bufA + (1*PIN + b)*SA + c) = s1;
                *reinterpret_cast<float4*>(bufA + (2*PIN + b)*SA + c) = s2;
            }
        }
        __syncthreads();
        tile_gemm44<C1, SA>(bufA, sW, bufB, TP, tid, nt);   // v = pre @ W
        __syncthreads();
        tile_gemm44<C1, SA>(bufB, sU, bufA, TP, tid, nt);   // d = v @ U
        __syncthreads();
        {   // parallel dot: 4 row-groups x 64 channels
            const int c = tid & 63, g = (tid >> 6) & 3;
            float dt = 0.f, dn = 0.f;
            for (int t = g; t < T; t += 4) {
                const float vv = bufB[t*SA + c], dd = bufA[t*SA + c];
                dt = fmaf(vv, dd, dt); dn = fmaf(dd, dd, dn);
            }
            pdt[g][c] = dt; pdn[g][c] = dn;
        }
        __syncthreads();
        if (tid < C1) {
            const float dt = pdt[0][tid]+pdt[1][tid]+pdt[2][tid]+pdt[3][tid];
            const float dn = pdn[0][tid]+pdn[1][tid]+pdn[2][tid]+pdn[3][tid];
            dotc[tid] = dt; psc[tid] = dt / (dn + VEPS);
        }
        __syncthreads();
        if (!LAST) {
            for (int e = tid; e < TC; e += nt) {
                const int t = e >> 6, c = e & 63;
                const float vv = bufB[t*SA + c], dd = bufA[t*SA + c];
                const float rr = (dotc[c] >= 0.f) ? vv : fmaf(-psc[c], dd, vv);
                vout[(size_t)pt * TC + e] = NEG*vv + (1.f-NEG)*rr;
            }
        } else {
            for (int e = tid; e < TC; e += nt) {
                const int t = e >> 6, c = e & 63;
                const float vv = bufB[t*SA + c], dd = bufA[t*SA + c];
                const float rr = (dotc[c] >= 0.f) ? vv : fmaf(-psc[c], dd, vv);
                bufB[t*SA + c] = NEG*vv + (1.f-NEG)*rr;
            }
            __syncthreads();
#pragma unroll
            for (int i = 0; i < NG; ++i) {
                const int e = i*256 + tid;
                if (e < TC) gacc[i] += bufB[(e >> 6)*SA + (e & 63)];
            }
            // six k=4 trace pairs, weighted by w4[:, :64]  ->  hv (pt, 9, 64)
            for (int e = tid; e < 9*C1; e += nt) {
                const int pq = e >> 6, c = e & 63;
                const int p = pq / 3, qq = pq - 3*p;
                float tr0=0,tr1=0,tr2=0,tr3=0,tr4=0,tr5=0;
#pragma unroll
                for (int r = 0; r < 3; ++r) {
                    tr0 += bufB[(r*36 + p*3 + qq )*SA + c];
                    tr1 += bufB[(r*30 + p*9 + qq )*SA + c];
                    tr2 += bufB[(r*28 + p*9 + qq*3)*SA + c];
                    tr3 += bufB[(p*27 + r*12 + qq )*SA + c];
                    tr4 += bufB[(p*27 + r*10 + qq*3)*SA + c];
                    tr5 += bufB[(p*27 + qq*9 + r*4 )*SA + c];
                }
                const float acc = w4[0*C2 + c]*tr0 + w4[1*C2 + c]*tr1 + w4[2*C2 + c]*tr2
                                + w4[3*C2 + c]*tr3 + w4[4*C2 + c]*tr4 + w4[5*C2 + c]*tr5;
                hv[(size_t)pt * (9*C1) + e] = acc;
            }
        }
        __syncthreads();
    }
    if (LAST) {
#pragma unroll
        for (int i = 0; i < NG; ++i) {
            const int e = i*256 + tid;
            if (e < TC) gpart[(size_t)blockIdx.x * TC + e] = gacc[i];
        }
    }
}

// ======================= g reduction + hg =======================
__global__ void reduce_g_kernel(const float* __restrict__ gpart, int nparts,
                                float* __restrict__ g)
{
    const int e = blockIdx.x * blockDim.x + threadIdx.x;
    if (e >= 81*C1) return;
    float s = 0.f;
    for (int b = 0; b < nparts; ++b) s += gpart[(size_t)b * (81*C1) + e];
    g[e] = s * (1.0f/NPTS);
}

__global__ void hg_kernel(const float* __restrict__ g, const float* __restrict__ w4,
                          float* __restrict__ hg)
{
    __shared__ float gs[81*C1];
    const int tid = threadIdx.x;
    for (int e = tid; e < 81*C1; e += blockDim.x) gs[e] = g[e];
    __syncthreads();
    for (int e = tid; e < 9*C1; e += blockDim.x) {
        const int pq = e >> 6, c = e & 63;
        const int p = pq / 3, qq = pq - 3*p;
        float tr0=0,tr1=0,tr2=0,tr3=0,tr4=0,tr5=0;
#pragma unroll
        for (int r = 0; r < 3; ++r) {
            tr0 += gs[(r*36 + p*3 + qq ) * C1 + c];
            tr1 += gs[(r*30 + p*9 + qq ) * C1 + c];
            tr2 += gs[(r*28 + p*9 + qq*3) * C1 + c];
            tr3 += gs[(p*27 + r*12 + qq ) * C1 + c];
            tr4 += gs[(p*27 + r*10 + qq*3) * C1 + c];
            tr5 += gs[(p*27 + qq*9 + r*4 ) * C1 + c];
        }
        hg[e] = w4[0*C2 + 64 + c]*tr0 + w4[1*C2 + 64 + c]*tr1 + w4[2*C2 + 64 + c]*tr2
              + w4[3*C2 + 64 + c]*tr3 + w4[4*C2 + 64 + c]*tr4 + w4[5*C2 + 64 + c]*tr5;
    }
}

// ======================= contraction head (unchanged) =======================
__global__ __launch_bounds__(256) void contract_kernel(const float* __restrict__ hv,
                                                       const float* __restrict__ hg,
                                                       const float* __restrict__ cW,
                                                       const float* __restrict__ cU,
                                                       const float* __restrict__ w2,
                                                       float* __restrict__ out,
                                                       int pts_per_block)
{
    __shared__ __align__(16) float sW[C2*C2];
    __shared__ __align__(16) float sU[C2*C2];
    __shared__ __align__(16) float h0[9*C2];
    __shared__ __align__(16) float h1[9*C2];
    __shared__ __align__(16) float h2[9*C2];
    __shared__ float hgs[9*C1];
    __shared__ float dotc[C2], psc[C2];

    const int tid = threadIdx.x, nt = blockDim.x;
    for (int e = tid; e < C2*C2; e += nt) { sW[e] = cW[e]; sU[e] = cU[e]; }
    for (int e = tid; e < 9*C1; e += nt) hgs[e] = hg[e];
    __syncthreads();

    const int p0 = blockIdx.x * pts_per_block;
    for (int pi = 0; pi < pts_per_block; ++pi) {
        const int pt = p0 + pi;
        for (int e = tid; e < 9*C2; e += nt) {
            const int t = e >> 7, c = e & 127;
            h0[e] = (c < C1) ? hv[(size_t)pt*(9*C1) + t*C1 + c] : hgs[t*C1 + (c - C1)];
        }
        __syncthreads();
        tile_gemm<C2>(h0, sW, h1, 9, tid, nt);
        __syncthreads();
        tile_gemm<C2>(h1, sU, h2, 9, tid, nt);
        __syncthreads();
        if (tid < C2) {
            float dt = 0.f, dn = 0.f;
            for (int t = 0; t < 9; ++t) {
                const float vv = h1[t*C2 + tid], dd = h2[t*C2 + tid];
                dt = fmaf(vv, dd, dt); dn = fmaf(dd, dd, dn);
            }
            dotc[tid] = dt; psc[tid] = dt / (dn + VEPS);
        }
        __syncthreads();
        if (tid < C2) {
            const int c = tid;
            float s = 0.f;
#pragma unroll
            for (int r = 0; r < 3; ++r) {
                const int t = r * 4;
                const float vv = h1[t*C2 + c], dd = h2[t*C2 + c];
                const float rr = (dotc[c] >= 0.f) ? vv : fmaf(-psc[c], dd, vv);
                s += NEG*vv + (1.f-NEG)*rr;
            }
            out[(size_t)pt*C2 + c] = w2[c] * s;
        }
        __syncthreads();
    }
}

// ======================= launcher =======================
extern "C" void kernel_launch(void* const* d_in, const int* in_sizes, int n_in,
                              void* d_out, int out_size, void* d_ws, size_t ws_size,
                              hipStream_t stream)
{
    (void)in_sizes; (void)n_in; (void)out_size; (void)ws_size;
    const float* x  = (const float*)d_in[0];
    const float* kW = (const float*)d_in[1];
    const float* kU = (const float*)d_in[2];
    const float* w4 = (const float*)d_in[3];
    const float* cW = (const float*)d_in[4];
    const float* cU = (const float*)d_in[5];
    const float* w2 = (const float*)d_in[6];
    float* out = (float*)d_out;

    char* ws = (char*)d_ws;
    size_t off = 0;
    auto alloc = [&](size_t bytes) -> void* {
        void* p = ws + off; off += (bytes + 255) & ~(size_t)255; return p;
    };
    int*   idx   = (int*)  alloc((size_t)NPTS*KNB*4);
    float* v1    = (float*)alloc((size_t)NPTS*3*C1*4);
    float* v2    = (float*)alloc((size_t)NPTS*9*C1*4);
    float* v3    = (float*)alloc((size_t)NPTS*27*C1*4);     // 56.6 MB; knn parts alias (32 MB)
    float* gpart = (float*)alloc((size_t)256*81*C1*4);
    float* g     = (float*)alloc((size_t)81*C1*4);
    float* hg    = (float*)alloc((size_t)9*C1*4);
    float* hv    = v2;                                       // v2 dead once v3 exists
    unsigned long long* parts = (unsigned long long*)v3;     // dead before v3 is written

    knn_part <<<1024, 256, 0, stream>>>(x, parts);
    knn_merge<<<NPTS/256, 256, 0, stream>>>(parts, idx);
    kron_step<1,  true,  false><<<512, 256, 0, stream>>>(x, idx, nullptr, kW,       kU,       v1, nullptr, nullptr, nullptr, 16);
    kron_step<3,  false, false><<<512, 256, 0, stream>>>(x, idx, v1,      kW+4096,  kU+4096,  v2, nullptr, nullptr, nullptr, 16);
    kron_step<9,  false, false><<<512, 256, 0, stream>>>(x, idx, v2,      kW+8192,  kU+8192,  v3, nullptr, nullptr, nullptr, 16);
    kron_step<27, false, true ><<<256, 256, 0, stream>>>(x, idx, v3,      kW+12288, kU+12288, nullptr, w4, hv, gpart, 32);
    reduce_g_kernel<<<(81*C1 + 255)/256, 256, 0, stream>>>(gpart, 256, g);
    hg_kernel<<<1, 256, 0, stream>>>(g, w4, hg);
    contract_kernel<<<256, 256, 0, stream>>>(hv, hg, cW, cU, w2, out, 32);
}

// Round 3
// 812.483 us; speedup vs baseline: 2.4613x; 1.9150x over previous
//
#include <hip/hip_runtime.h>
#include <math.h>

#define NPTS 8192
#define KNB  16
#define C1   64
#define C2   128
#define NEG  0.2f
#define VEPS 1e-6f
#define NCH  32
#define CHSZ (NPTS/NCH)   // 256

// ======================= KNN phase 1: per-chunk top-16 =======================
__global__ __launch_bounds__(256) void knn_part(const float* __restrict__ x,
                                                unsigned long long* __restrict__ parts)
{
    __shared__ __align__(16) float4 cpt[CHSZ];
    __shared__ unsigned long long sbuf[256 * 8];

    const int tid   = threadIdx.x;
    const int chunk = blockIdx.x & (NCH - 1);
    const int qg    = blockIdx.x >> 5;
    const int j0    = chunk * CHSZ;

    cpt[tid] = make_float4(x[3*(j0+tid)+0], x[3*(j0+tid)+1], x[3*(j0+tid)+2], 0.f);
    const int q = qg * 256 + tid;
    const float qx = x[3*q+0], qy = x[3*q+1], qz = x[3*q+2];
    __syncthreads();

    unsigned long long bd[16];
#pragma unroll
    for (int r = 0; r < 16; ++r) bd[r] = ~0ull;
    int cnt = 0;
    unsigned long long* mybuf = sbuf + tid * 8;

    auto flush = [&]() {
#pragma unroll
        for (int s = 0; s < 8; ++s) {
            if (s < cnt) {
                const unsigned long long k = mybuf[s];
                if (k < bd[15]) {
#pragma unroll
                    for (int p2 = 15; p2 > 0; --p2) {
                        const bool sh = k < bd[p2-1];
                        const bool pl = k < bd[p2];
                        bd[p2] = sh ? bd[p2-1] : (pl ? k : bd[p2]);
                    }
                    if (k < bd[0]) bd[0] = k;
                }
            }
        }
        cnt = 0;
    };

    for (int jj = 0; jj < CHSZ; ++jj) {
        const float4 p = cpt[jj];
        const float dx = qx - p.x, dy = qy - p.y, dz = qz - p.z;
        const double ddx = (double)dx, ddy = (double)dy, ddz = (double)dz;
        const double d2 = ddx*ddx + ddy*ddy + ddz*ddz;
        const unsigned long long key =
            (((unsigned long long)__double_as_longlong(d2)) & ~8191ull)
            | (unsigned long long)(j0 + jj);
        if (key < bd[15]) { mybuf[cnt] = key; ++cnt; }
        if (__any(cnt >= 8)) flush();
    }
    flush();

#pragma unroll
    for (int r = 0; r < 16; ++r)
        parts[((size_t)chunk * KNB + r) * NPTS + q] = bd[r];
}

// ======================= KNN phase 2: 32-way sorted merge =======================
__global__ __launch_bounds__(256) void knn_merge(const unsigned long long* __restrict__ parts,
                                                 int* __restrict__ idx_out)
{
    __shared__ unsigned char heads[256][NCH];
    const int tid = threadIdx.x;
    const int q = blockIdx.x * 256 + tid;
    unsigned char* h = heads[tid];
#pragma unroll
    for (int c = 0; c < NCH; ++c) h[c] = 0;
    for (int r = 0; r < KNB; ++r) {
        unsigned long long best = ~0ull; int bc = 0;
#pragma unroll
        for (int c = 0; c < NCH; ++c) {
            const unsigned long long k = parts[((size_t)c * KNB + h[c]) * NPTS + q];
            if (k < best) { best = k; bc = c; }
        }
        h[bc]++;
        idx_out[q*KNB + r] = (int)(best & 8191ull);
    }
}

// ======================= 4x4 register-tile GEMM (LDS B, width 64) ==============
#define FMA4(ar, b0, b1, b2, b3, acc) \
    acc.x = fmaf(ar.x,b0.x, fmaf(ar.y,b1.x, fmaf(ar.z,b2.x, fmaf(ar.w,b3.x, acc.x)))); \
    acc.y = fmaf(ar.x,b0.y, fmaf(ar.y,b1.y, fmaf(ar.z,b2.y, fmaf(ar.w,b3.y, acc.y)))); \
    acc.z = fmaf(ar.x,b0.z, fmaf(ar.y,b1.z, fmaf(ar.z,b2.z, fmaf(ar.w,b3.z, acc.z)))); \
    acc.w = fmaf(ar.x,b0.w, fmaf(ar.y,b1.w, fmaf(ar.z,b2.w, fmaf(ar.w,b3.w, acc.w))));

template<int W, int SA>
__device__ __forceinline__ void tile_gemm44(const float* __restrict__ A,
                                            const float* __restrict__ B,
                                            float* __restrict__ Cc,
                                            int TP, int tid, int nt)
{
    constexpr int DQ = W / 4;
    const int nunits = (TP >> 2) * DQ;
    for (int u = tid; u < nunits; u += nt) {
        const int tg = u / DQ;
        const int d  = (u - tg * DQ) * 4;
        const float* a0p = A + (tg*4+0)*SA;
        const float* a1p = A + (tg*4+1)*SA;
        const float* a2p = A + (tg*4+2)*SA;
        const float* a3p = A + (tg*4+3)*SA;
        float4 acc0 = {0,0,0,0}, acc1 = acc0, acc2 = acc0, acc3 = acc0;
        for (int c = 0; c < W; c += 4) {
            const float4 a0 = *reinterpret_cast<const float4*>(a0p + c);
            const float4 a1 = *reinterpret_cast<const float4*>(a1p + c);
            const float4 a2 = *reinterpret_cast<const float4*>(a2p + c);
            const float4 a3 = *reinterpret_cast<const float4*>(a3p + c);
            const float4 b0 = *reinterpret_cast<const float4*>(B + (c+0)*W + d);
            const float4 b1 = *reinterpret_cast<const float4*>(B + (c+1)*W + d);
            const float4 b2 = *reinterpret_cast<const float4*>(B + (c+2)*W + d);
            const float4 b3 = *reinterpret_cast<const float4*>(B + (c+3)*W + d);
            FMA4(a0, b0, b1, b2, b3, acc0);
            FMA4(a1, b0, b1, b2, b3, acc1);
            FMA4(a2, b0, b1, b2, b3, acc2);
            FMA4(a3, b0, b1, b2, b3, acc3);
        }
        *reinterpret_cast<float4*>(Cc + (tg*4+0)*SA + d) = acc0;
        *reinterpret_cast<float4*>(Cc + (tg*4+1)*SA + d) = acc1;
        *reinterpret_cast<float4*>(Cc + (tg*4+2)*SA + d) = acc2;
        *reinterpret_cast<float4*>(Cc + (tg*4+3)*SA + d) = acc3;
    }
}

// ======================= W-hoisted Kronecker step =======================
// in:  yin = (prev relu-out @ W_this), gathered -> v directly (no GEMM1)
// out: yout = relu(v, U) @ Wnext   (or traces/g when LAST)
template<int PIN, bool FIRST, bool LAST>
__global__ __launch_bounds__(256) void kron2(const float* __restrict__ x,
                                             const int* __restrict__ idxs,
                                             const float* __restrict__ yin,
                                             const float* __restrict__ Wfirst,
                                             const float* __restrict__ Um,
                                             const float* __restrict__ Wnext,
                                             float* __restrict__ yout,
                                             const float* __restrict__ w4,
                                             float* __restrict__ hv,
                                             float* __restrict__ gpart,
                                             int ppb)
{
    constexpr int T  = 3 * PIN;
    constexpr int TP = (T + 3) & ~3;
    constexpr int SA = C1 + 4;
    constexpr int TC = T * C1;
    constexpr int PC = PIN * C1;
    constexpr int NG = LAST ? (TC + 255) / 256 : 1;

    __shared__ __align__(16) float sU[C1*C1];
    __shared__ __align__(16) float sWn[LAST ? 4 : C1*C1];
    __shared__ __align__(16) float bufV[TP*SA];
    __shared__ __align__(16) float bufD[TP*SA];
    __shared__ float xg[KNB*3];
    __shared__ int   ids[KNB];
    __shared__ float dotc[C1], psc[C1];
    __shared__ float pdt[4][C1], pdn[4][C1];
    __shared__ float mx[4];
    __shared__ float Scol[FIRST ? C1 : 4];

    const int tid = threadIdx.x;
    const int nt  = 256;

    for (int e = tid; e < C1*C1; e += nt) sU[e] = Um[e];
    if (!LAST) for (int e = tid; e < C1*C1; e += nt) sWn[e] = Wnext[e];
    if (FIRST && tid < C1) {
        float s = 0.f;
        for (int j = 0; j < C1; ++j) s += Wfirst[j*C1 + tid];
        Scol[tid] = s;
    }
    for (int e = tid; e < (TP - T) * C1; e += nt)
        bufV[(T + (e >> 6))*SA + (e & 63)] = 0.f;
    float gacc[NG];
#pragma unroll
    for (int i = 0; i < NG; ++i) gacc[i] = 0.f;
    __syncthreads();

    const int p0 = blockIdx.x * ppb;
    for (int pi = 0; pi < ppb; ++pi) {
        const int pt = p0 + pi;
        if (tid < KNB) ids[tid] = idxs[pt*KNB + tid];
        if (tid >= 64 && tid < 64 + KNB*3) {
            const int t2 = tid - 64, k = t2 / 3, a = t2 - 3*k;
            xg[t2] = x[3*idxs[pt*KNB + k] + a];
        }
        __syncthreads();

        if (FIRST) {
            if (tid < 3) {
                float s = 0.f;
                for (int k = 0; k < KNB; ++k) s += xg[k*3 + tid];
                mx[tid] = s * (1.0f/KNB);
            }
            __syncthreads();
            for (int e = tid; e < TC; e += nt)
                bufV[(e >> 6)*SA + (e & 63)] = mx[e >> 6] * Scol[e & 63];
        } else {
            for (int e4 = tid * 4; e4 < PC; e4 += nt * 4) {
                float4 s0 = {0,0,0,0}, s1 = {0,0,0,0}, s2 = {0,0,0,0};
#pragma unroll
                for (int k = 0; k < KNB; ++k) {
                    const float4 val = *reinterpret_cast<const float4*>(yin + (size_t)ids[k]*PC + e4);
                    const float xa = xg[k*3+0], xb = xg[k*3+1], xc = xg[k*3+2];
                    s0.x = fmaf(xa, val.x, s0.x); s0.y = fmaf(xa, val.y, s0.y);
                    s0.z = fmaf(xa, val.z, s0.z); s0.w = fmaf(xa, val.w, s0.w);
                    s1.x = fmaf(xb, val.x, s1.x); s1.y = fmaf(xb, val.y, s1.y);
                    s1.z = fmaf(xb, val.z, s1.z); s1.w = fmaf(xb, val.w, s1.w);
                    s2.x = fmaf(xc, val.x, s2.x); s2.y = fmaf(xc, val.y, s2.y);
                    s2.z = fmaf(xc, val.z, s2.z); s2.w = fmaf(xc, val.w, s2.w);
                }
                const float inv = 1.0f / KNB;
                s0.x*=inv; s0.y*=inv; s0.z*=inv; s0.w*=inv;
                s1.x*=inv; s1.y*=inv; s1.z*=inv; s1.w*=inv;
                s2.x*=inv; s2.y*=inv; s2.z*=inv; s2.w*=inv;
                const int b = e4 >> 6, c = e4 & 63;
                *reinterpret_cast<float4*>(bufV + (0*PIN + b)*SA + c) = s0;
                *reinterpret_cast<float4*>(bufV + (1*PIN + b)*SA + c) = s1;
                *reinterpret_cast<float4*>(bufV + (2*PIN + b)*SA + c) = s2;
            }
        }
        __syncthreads();
        tile_gemm44<C1, SA>(bufV, sU, bufD, TP, tid, nt);   // d = v @ U
        __syncthreads();
        {
            const int c = tid & 63, g4 = (tid >> 6) & 3;
            float dt = 0.f, dn = 0.f;
            for (int t = g4; t < T; t += 4) {
                const float vv = bufV[t*SA + c], dd = bufD[t*SA + c];
                dt = fmaf(vv, dd, dt); dn = fmaf(dd, dd, dn);
            }
            pdt[g4][c] = dt; pdn[g4][c] = dn;
        }
        __syncthreads();
        if (tid < C1) {
            const float dt = pdt[0][tid]+pdt[1][tid]+pdt[2][tid]+pdt[3][tid];
            const float dn = pdn[0][tid]+pdn[1][tid]+pdn[2][tid]+pdn[3][tid];
            dotc[tid] = dt; psc[tid] = dt / (dn + VEPS);
        }
        __syncthreads();
        // relu in place: rout = NEG*v + (1-NEG)*(dot>=0 ? v : v - psc*d)
        for (int e = tid; e < TC; e += nt) {
            const int t = e >> 6, c = e & 63;
            const float vv = bufV[t*SA + c], dd = bufD[t*SA + c];
            const float rr = (dotc[c] >= 0.f) ? vv : fmaf(-psc[c], dd, vv);
            bufV[t*SA + c] = NEG*vv + (1.f-NEG)*rr;
        }
        __syncthreads();
        if (!LAST) {
            // yout = rout @ Wnext  -> global (guarded rows)
            for (int u = tid; u < (TP >> 2) * 16; u += nt) {
                const int tg = u >> 4;
                const int d  = (u & 15) * 4;
                const float* a0p = bufV + (tg*4+0)*SA;
                const float* a1p = bufV + (tg*4+1)*SA;
                const float* a2p = bufV + (tg*4+2)*SA;
                const float* a3p = bufV + (tg*4+3)*SA;
                float4 acc0 = {0,0,0,0}, acc1 = acc0, acc2 = acc0, acc3 = acc0;
                for (int c = 0; c < C1; c += 4) {
                    const float4 a0 = *reinterpret_cast<const float4*>(a0p + c);
                    const float4 a1 = *reinterpret_cast<const float4*>(a1p + c);
                    const float4 a2 = *reinterpret_cast<const float4*>(a2p + c);
                    const float4 a3 = *reinterpret_cast<const float4*>(a3p + c);
                    const float4 b0 = *reinterpret_cast<const float4*>(sWn + (c+0)*C1 + d);
                    const float4 b1 = *reinterpret_cast<const float4*>(sWn + (c+1)*C1 + d);
                    const float4 b2 = *reinterpret_cast<const float4*>(sWn + (c+2)*C1 + d);
                    const float4 b3 = *reinterpret_cast<const float4*>(sWn + (c+3)*C1 + d);
                    FMA4(a0, b0, b1, b2, b3, acc0);
                    FMA4(a1, b0, b1, b2, b3, acc1);
                    FMA4(a2, b0, b1, b2, b3, acc2);
                    FMA4(a3, b0, b1, b2, b3, acc3);
                }
                float* op = yout + (size_t)pt * TC;
                if (tg*4+0 < T) *reinterpret_cast<float4*>(op + (tg*4+0)*C1 + d) = acc0;
                if (tg*4+1 < T) *reinterpret_cast<float4*>(op + (tg*4+1)*C1 + d) = acc1;
                if (tg*4+2 < T) *reinterpret_cast<float4*>(op + (tg*4+2)*C1 + d) = acc2;
                if (tg*4+3 < T) *reinterpret_cast<float4*>(op + (tg*4+3)*C1 + d) = acc3;
            }
        } else {
#pragma unroll
            for (int i = 0; i < NG; ++i) {
                const int e = i*256 + tid;
                if (e < TC) gacc[i] += bufV[(e >> 6)*SA + (e & 63)];
            }
            for (int e = tid; e < 9*C1; e += nt) {
                const int pq = e >> 6, c = e & 63;
                const int p = pq / 3, qq = pq - 3*p;
                float tr0=0,tr1=0,tr2=0,tr3=0,tr4=0,tr5=0;
#pragma unroll
                for (int r = 0; r < 3; ++r) {
                    tr0 += bufV[(r*36 + p*3 + qq )*SA + c];
                    tr1 += bufV[(r*30 + p*9 + qq )*SA + c];
                    tr2 += bufV[(r*28 + p*9 + qq*3)*SA + c];
                    tr3 += bufV[(p*27 + r*12 + qq )*SA + c];
                    tr4 += bufV[(p*27 + r*10 + qq*3)*SA + c];
                    tr5 += bufV[(p*27 + qq*9 + r*4 )*SA + c];
                }
                const float acc = w4[0*C2 + c]*tr0 + w4[1*C2 + c]*tr1 + w4[2*C2 + c]*tr2
                                + w4[3*C2 + c]*tr3 + w4[4*C2 + c]*tr4 + w4[5*C2 + c]*tr5;
                hv[(size_t)pt * (9*C1) + e] = acc;
            }
        }
        __syncthreads();
    }
    if (LAST) {
#pragma unroll
        for (int i = 0; i < NG; ++i) {
            const int e = i*256 + tid;
            if (e < TC) gpart[(size_t)blockIdx.x * TC + e] = gacc[i];
        }
    }
}

// ======================= g reduction =======================
// grid 324 x 256: 16 elems/block, 16 part-groups; NPARTS=512
__global__ __launch_bounds__(256) void reduce_g_kernel(const float* __restrict__ gpart,
                                                       float* __restrict__ g)
{
    __shared__ float red[256];
    const int el = threadIdx.x & 15, pg = threadIdx.x >> 4;
    const int e = blockIdx.x * 16 + el;
    float s = 0.f;
    for (int p = pg; p < 512; p += 16) s += gpart[(size_t)p * (81*C1) + e];
    red[threadIdx.x] = s;
    __syncthreads();
    for (int st = 8; st > 0; st >>= 1) {
        if (pg < st) red[el + 16*pg] += red[el + 16*(pg+st)];
        __syncthreads();
    }
    if (pg == 0) g[e] = red[el] * (1.0f/NPTS);
}

// ======================= hg + hgW precompute =======================
// hg (9x64) = w4[:,64:]-weighted traces of g; hgW (9x128) = hg @ cW[64:,:]
__global__ __launch_bounds__(256) void hgw_kernel(const float* __restrict__ g,
                                                  const float* __restrict__ w4,
                                                  const float* __restrict__ cW,
                                                  float* __restrict__ hgW)
{
    __shared__ float gs[81*C1];
    __shared__ float hg[9*C1];
    const int tid = threadIdx.x;
    for (int e = tid; e < 81*C1; e += 256) gs[e] = g[e];
    __syncthreads();
    for (int e = tid; e < 9*C1; e += 256) {
        const int pq = e >> 6, c = e & 63;
        const int p = pq / 3, qq = pq - 3*p;
        float tr0=0,tr1=0,tr2=0,tr3=0,tr4=0,tr5=0;
#pragma unroll
        for (int r = 0; r < 3; ++r) {
            tr0 += gs[(r*36 + p*3 + qq ) * C1 + c];
            tr1 += gs[(r*30 + p*9 + qq ) * C1 + c];
            tr2 += gs[(r*28 + p*9 + qq*3) * C1 + c];
            tr3 += gs[(p*27 + r*12 + qq ) * C1 + c];
            tr4 += gs[(p*27 + r*10 + qq*3) * C1 + c];
            tr5 += gs[(p*27 + qq*9 + r*4 ) * C1 + c];
        }
        hg[e] = w4[0*C2 + 64 + c]*tr0 + w4[1*C2 + 64 + c]*tr1 + w4[2*C2 + 64 + c]*tr2
              + w4[3*C2 + 64 + c]*tr3 + w4[4*C2 + 64 + c]*tr4 + w4[5*C2 + 64 + c]*tr5;
    }
    __syncthreads();
    for (int o = tid; o < 9*C2; o += 256) {
        const int t = o >> 7, c = o & 127;
        float s = 0.f;
        for (int j = 0; j < C1; ++j) s = fmaf(hg[t*C1 + j], cW[(C1+j)*C2 + c], s);
        hgW[o] = s;
    }
}

// ======================= contraction head =======================
// 4 points/iter; h1 = hv@cW_top + hgW ; h2 = h1@cU ; weights from global.
__global__ __launch_bounds__(256) void contract_kernel(const float* __restrict__ hv,
                                                       const float* __restrict__ hgW,
                                                       const float* __restrict__ cW,
                                                       const float* __restrict__ cU,
                                                       const float* __restrict__ w2,
                                                       float* __restrict__ out,
                                                       int ppb)
{
    constexpr int S0 = C1 + 4;    // 68
    constexpr int SH = C2 + 4;    // 132
    __shared__ __align__(16) float h0[36*S0];
    __shared__ __align__(16) float h1[36*SH];
    __shared__ __align__(16) float h2[36*SH];
    __shared__ __align__(16) float hgs[9*C2];

    const int tid = threadIdx.x;
    for (int e = tid; e < 9*C2; e += 256) hgs[e] = hgW[e];
    __syncthreads();

    const int iters = ppb >> 2;
    for (int it = 0; it < iters; ++it) {
        const int base = blockIdx.x * ppb + it * 4;
        for (int e = tid; e < 4*9*C1; e += 256) {
            const int pt = e / 576, rem = e - pt*576;
            const int t = rem >> 6, c = rem & 63;
            h0[(pt*9 + t)*S0 + c] = hv[(size_t)(base+pt)*576 + rem];
        }
        __syncthreads();
        // GEMM1: h1(36x128) = h0(36x64) @ cW[0:64,:] + hgW  (acc init from hgW)
        for (int u = tid; u < 9*32; u += 256) {
            const int tg = u >> 5;
            const int d  = (u & 31) * 4;
            const int r0 = tg*4;
            float4 acc0 = *reinterpret_cast<const float4*>(hgs + ((r0+0)%9)*C2 + d);
            float4 acc1 = *reinterpret_cast<const float4*>(hgs + ((r0+1)%9)*C2 + d);
            float4 acc2 = *reinterpret_cast<const float4*>(hgs + ((r0+2)%9)*C2 + d);
            float4 acc3 = *reinterpret_cast<const float4*>(hgs + ((r0+3)%9)*C2 + d);
            for (int c = 0; c < C1; c += 4) {
                const float4 a0 = *reinterpret_cast<const float4*>(h0 + (r0+0)*S0 + c);
                const float4 a1 = *reinterpret_cast<const float4*>(h0 + (r0+1)*S0 + c);
                const float4 a2 = *reinterpret_cast<const float4*>(h0 + (r0+2)*S0 + c);
                const float4 a3 = *reinterpret_cast<const float4*>(h0 + (r0+3)*S0 + c);
                const float4 b0 = *reinterpret_cast<const float4*>(cW + (c+0)*C2 + d);
                const float4 b1 = *reinterpret_cast<const float4*>(cW + (c+1)*C2 + d);
                const float4 b2 = *reinterpret_cast<const float4*>(cW + (c+2)*C2 + d);
                const float4 b3 = *reinterpret_cast<const float4*>(cW + (c+3)*C2 + d);
                FMA4(a0, b0, b1, b2, b3, acc0);
                FMA4(a1, b0, b1, b2, b3, acc1);
                FMA4(a2, b0, b1, b2, b3, acc2);
                FMA4(a3, b0, b1, b2, b3, acc3);
            }
            *reinterpret_cast<float4*>(h1 + (r0+0)*SH + d) = acc0;
            *reinterpret_cast<float4*>(h1 + (r0+1)*SH + d) = acc1;
            *reinterpret_cast<float4*>(h1 + (r0+2)*SH + d) = acc2;
            *reinterpret_cast<float4*>(h1 + (r0+3)*SH + d) = acc3;
        }
        __syncthreads();
        // GEMM2: h2(36x128) = h1 @ cU (K=128)
        for (int u = tid; u < 9*32; u += 256) {
            const int tg = u >> 5;
            const int d  = (u & 31) * 4;
            const int r0 = tg*4;
            float4 acc0 = {0,0,0,0}, acc1 = acc0, acc2 = acc0, acc3 = acc0;
            for (int c = 0; c < C2; c += 4) {
                const float4 a0 = *reinterpret_cast<const float4*>(h1 + (r0+0)*SH + c);
                const float4 a1 = *reinterpret_cast<const float4*>(h1 + (r0+1)*SH + c);
                const float4 a2 = *reinterpret_cast<const float4*>(h1 + (r0+2)*SH + c);
                const float4 a3 = *reinterpret_cast<const float4*>(h1 + (r0+3)*SH + c);
                const float4 b0 = *reinterpret_cast<const float4*>(cU + (c+0)*C2 + d);
                const float4 b1 = *reinterpret_cast<const float4*>(cU + (c+1)*C2 + d);
                const float4 b2 = *reinterpret_cast<const float4*>(cU + (c+2)*C2 + d);
                const float4 b3 = *reinterpret_cast<const float4*>(cU + (c+3)*C2 + d);
                FMA4(a0, b0, b1, b2, b3, acc0);
                FMA4(a1, b0, b1, b2, b3, acc1);
                FMA4(a2, b0, b1, b2, b3, acc2);
                FMA4(a3, b0, b1, b2, b3, acc3);
            }
            *reinterpret_cast<float4*>(h2 + (r0+0)*SH + d) = acc0;
            *reinterpret_cast<float4*>(h2 + (r0+1)*SH + d) = acc1;
            *reinterpret_cast<float4*>(h2 + (r0+2)*SH + d) = acc2;
            *reinterpret_cast<float4*>(h2 + (r0+3)*SH + d) = acc3;
        }
        __syncthreads();
        // stats + relu + final trace, fully thread-local per (pt, c)
#pragma unroll
        for (int p2 = 0; p2 < 2; ++p2) {
            const int pair = tid + 256*p2;
            const int pt = pair >> 7, c = pair & 127;
            float dt = 0.f, dn = 0.f;
            for (int t = 0; t < 9; ++t) {
                const float vv = h1[(pt*9+t)*SH + c], dd = h2[(pt*9+t)*SH + c];
                dt = fmaf(vv, dd, dt); dn = fmaf(dd, dd, dn);
            }
            const float ps = dt / (dn + VEPS);
            float s = 0.f;
#pragma unroll
            for (int r = 0; r < 3; ++r) {
                const int t = r * 4;
                const float vv = h1[(pt*9+t)*SH + c], dd = h2[(pt*9+t)*SH + c];
                const float rr = (dt >= 0.f) ? vv : fmaf(-ps, dd, vv);
                s += NEG*vv + (1.f-NEG)*rr;
            }
            out[(size_t)(base+pt)*C2 + c] = w2[c] * s;
        }
        __syncthreads();
    }
}

// ======================= launcher =======================
extern "C" void kernel_launch(void* const* d_in, const int* in_sizes, int n_in,
                              void* d_out, int out_size, void* d_ws, size_t ws_size,
                              hipStream_t stream)
{
    (void)in_sizes; (void)n_in; (void)out_size; (void)ws_size;
    const float* x  = (const float*)d_in[0];
    const float* kW = (const float*)d_in[1];
    const float* kU = (const float*)d_in[2];
    const float* w4 = (const float*)d_in[3];
    const float* cW = (const float*)d_in[4];
    const float* cU = (const float*)d_in[5];
    const float* w2 = (const float*)d_in[6];
    float* out = (float*)d_out;

    char* ws = (char*)d_ws;
    size_t off = 0;
    auto alloc = [&](size_t bytes) -> void* {
        void* p = ws + off; off += (bytes + 255) & ~(size_t)255; return p;
    };
    int*   idx   = (int*)  alloc((size_t)NPTS*KNB*4);
    float* y1    = (float*)alloc((size_t)NPTS*3*C1*4);       // 6.3 MB
    float* y2    = (float*)alloc((size_t)NPTS*9*C1*4);       // 18.9 MB (hv alias)
    float* y3    = (float*)alloc((size_t)NPTS*27*C1*4);      // 56.6 MB (knn parts alias)
    float* gpart = (float*)alloc((size_t)512*81*C1*4);       // 10.6 MB
    float* g     = (float*)alloc((size_t)81*C1*4);
    float* hgW   = (float*)alloc((size_t)9*C2*4);
    float* hv    = y2;                                       // y2 dead after step3
    unsigned long long* parts = (unsigned long long*)y3;     // dead before y3 written

    knn_part <<<1024, 256, 0, stream>>>(x, parts);
    knn_merge<<<NPTS/256, 256, 0, stream>>>(parts, idx);
    kron2<1,  true,  false><<<1024, 256, 0, stream>>>(x, idx, nullptr, kW, kU,        kW+4096,  y1, nullptr, nullptr, nullptr, 8);
    kron2<3,  false, false><<<1024, 256, 0, stream>>>(x, idx, y1, nullptr, kU+4096,   kW+8192,  y2, nullptr, nullptr, nullptr, 8);
    kron2<9,  false, false><<<1024, 256, 0, stream>>>(x, idx, y2, nullptr, kU+8192,   kW+12288, y3, nullptr, nullptr, nullptr, 8);
    kron2<27, false, true ><<<512,  256, 0, stream>>>(x, idx, y3, nullptr, kU+12288,  nullptr,  nullptr, w4, hv, gpart, 16);
    reduce_g_kernel<<<324, 256, 0, stream>>>(gpart, g);
    hgw_kernel<<<1, 256, 0, stream>>>(g, w4, cW, hgW);
    contract_kernel<<<1024, 256, 0, stream>>>(hv, hgW, cW, cU, w2, out, 8);
}